// Round 11
// baseline (183.619 us; speedup 1.0000x reference)
//
#include <hip/hip_runtime.h>
#include <hip/hip_bf16.h>

constexpr int NPIX = 4096;   // H*W
constexpr int NB   = 2;      // batch
constexpr int MS   = 8;      // m-split for attention (grid.y)
constexpr int NPART  = 16;   // BN partials per channel

// K=16 QK MFMA if the builtin exists on this toolchain (gfx950 ISA has the
// instruction); otherwise fall back to K=32 with 32-wide padded f/g rows.
#if defined(__has_builtin)
#if __has_builtin(__builtin_amdgcn_mfma_f32_16x16x16bf16_1k)
#define QK_K16 1
#endif
#endif
#ifndef QK_K16
#define QK_K16 0
#endif
constexpr int FW = QK_K16 ? 16 : 32;   // f/g row width (bf16 elems)

typedef __attribute__((ext_vector_type(8))) short bf16x8;
typedef __attribute__((ext_vector_type(4))) short bf16x4;
typedef __attribute__((ext_vector_type(4))) float f32x4;

__device__ inline float bf2f(unsigned short u) {
  unsigned v = (unsigned)u << 16;
  return __builtin_bit_cast(float, v);
}

// ---------------------------------------------------------------------------
// Per-channel fused BN affine from partials: sc = rstd*g, sb = bb - mean*sc
// ---------------------------------------------------------------------------
__device__ inline float2 bn_coeff(const float* __restrict__ psum, const float* __restrict__ psq,
                                  const float* __restrict__ g, const float* __restrict__ bb, int c) {
  float s = 0.f, s2 = 0.f;
#pragma unroll
  for (int p = 0; p < NPART; ++p) {
    s  += psum[(size_t)c * NPART + p];
    s2 += psq [(size_t)c * NPART + p];
  }
  const float inv = 1.f / (NB * NPIX);
  float m = s * inv;
  float var = s2 * inv - m * m;
  float r = rsqrtf(var + 1e-5f) * g[c];
  return float2{r, bb[c] - m * r};
}

// ---------------------------------------------------------------------------
// conv1x1 fp32 + fused BN partial stats. Optional bf16 y output (stats stay
// exact fp32 from registers). CPT out-channels x PX pixels per thread.
// grid = (NPIX/(256*PX), Co/CPT, NB).
// ---------------------------------------------------------------------------
template <int CPT, int PX, bool BF16OUT>
__global__ __launch_bounds__(256) void conv_stats_k(
    const float* __restrict__ x, const float* __restrict__ w,
    const float* __restrict__ bias, void* __restrict__ yout,
    float* __restrict__ psum, float* __restrict__ psq, int Ci, int Co) {
  constexpr int XB = NPIX / (256 * PX);
  const int t  = threadIdx.x;
  const int n  = (blockIdx.x * 256 + t) * PX;
  const int d0 = blockIdx.y * CPT;
  const int b  = blockIdx.z;
  float a[CPT][PX];
#pragma unroll
  for (int j = 0; j < CPT; ++j) {
    float bv = bias ? bias[d0 + j] : 0.f;
#pragma unroll
    for (int p = 0; p < PX; ++p) a[j][p] = bv;
  }
  const float* xb = x + ((size_t)b * Ci) * NPIX + n;
  const float* wr = w + d0;
#pragma unroll 2
  for (int c = 0; c < Ci; ++c) {
    float xv[PX];
    if constexpr (PX == 2) *(float2*)xv = *(const float2*)(xb + (size_t)c * NPIX);
    else                   *(float4*)xv = *(const float4*)(xb + (size_t)c * NPIX);
#pragma unroll
    for (int j = 0; j < CPT; ++j) {
      float wj = wr[j];
#pragma unroll
      for (int p = 0; p < PX; ++p) a[j][p] += xv[p] * wj;
    }
    wr += Co;
  }
  if constexpr (BF16OUT) {
    __hip_bfloat16* yb = (__hip_bfloat16*)yout + ((size_t)b * Co + d0) * NPIX + n;
#pragma unroll
    for (int j = 0; j < CPT; ++j) {
      __hip_bfloat162 tv;
      tv.x = __float2bfloat16(a[j][0]); tv.y = __float2bfloat16(a[j][1]);
      *(unsigned*)(yb + (size_t)j * NPIX) = *(unsigned*)&tv;
    }
  } else {
    float* yb = (float*)yout + ((size_t)b * Co + d0) * NPIX + n;
#pragma unroll
    for (int j = 0; j < CPT; ++j) {
      if constexpr (PX == 2) *(float2*)(yb + (size_t)j * NPIX) = *(float2*)a[j];
      else                   *(float4*)(yb + (size_t)j * NPIX) = *(float4*)a[j];
    }
  }

  float s[CPT], s2[CPT];
#pragma unroll
  for (int j = 0; j < CPT; ++j) {
    s[j] = 0.f; s2[j] = 0.f;
#pragma unroll
    for (int p = 0; p < PX; ++p) { s[j] += a[j][p]; s2[j] += a[j][p] * a[j][p]; }
  }
#pragma unroll
  for (int j = 0; j < CPT; ++j) {
    for (int d = 1; d < 64; d <<= 1) {
      s[j]  += __shfl_xor(s[j], d);
      s2[j] += __shfl_xor(s2[j], d);
    }
  }
  __shared__ float shA[4][CPT];
  __shared__ float shB[4][CPT];
  const int wave = t >> 6, lane = t & 63;
  if (lane == 0) {
#pragma unroll
    for (int j = 0; j < CPT; ++j) { shA[wave][j] = s[j]; shB[wave][j] = s2[j]; }
  }
  __syncthreads();
  if (t < CPT) {
    const int p = b * XB + blockIdx.x;
    psum[(size_t)(d0 + t) * NPART + p] = (shA[0][t] + shA[1][t]) + (shA[2][t] + shA[3][t]);
    psq [(size_t)(d0 + t) * NPART + p] = (shB[0][t] + shB[1][t]) + (shB[2][t] + shB[3][t]);
  }
}

// ---------------------------------------------------------------------------
// Fused q/k/v producer. BN+ReLU of y inline (coeffs from partials).
// blockIdx.y slices:
//   [0, Co/4)             : h conv, 4 channels x 2 pixels -> h3 [B][N/32][CO][32]
//   [Co/4, Co/4+CF/2)     : 2 f-channels + 2 g-channels x 2 pixels -> fqT/gqT
//   Co/4+CF/2             : zero channel pads [CF,FW) of fqT/gqT
// grid = (8, Co/4+CF/2+1, NB), 256 threads.
// ---------------------------------------------------------------------------
template <int CF>
__global__ __launch_bounds__(256) void qkv_k(
    const float* __restrict__ y,
    const float* __restrict__ psum, const float* __restrict__ psq,
    const float* __restrict__ bn_g, const float* __restrict__ bn_b,
    const float* __restrict__ wh, const float* __restrict__ bh,
    const float* __restrict__ wf, const float* __restrict__ bfv,
    const float* __restrict__ wg, const float* __restrict__ bgv,
    __hip_bfloat16* __restrict__ h3, __hip_bfloat16* __restrict__ fqT,
    __hip_bfloat16* __restrict__ gqT, int Ci, int Co) {
  const int t = threadIdx.x;
  const int n = (blockIdx.x * 256 + t) * 2;
  const int b = blockIdx.z;
  const int slice = blockIdx.y;
  const int NH = Co / 4;

  if (slice == NH + CF / 2) {   // pad-zero slice
    if (CF < FW) {
#pragma unroll
      for (int px = 0; px < 2; ++px) {
        __hip_bfloat16* fp = fqT + ((size_t)b * NPIX + n + px) * FW;
        __hip_bfloat16* gp = gqT + ((size_t)b * NPIX + n + px) * FW;
        for (int j = CF; j < FW; j += 2) {
          *(unsigned*)(fp + j) = 0u;
          *(unsigned*)(gp + j) = 0u;
        }
      }
    }
    return;
  }

  __shared__ float s_sc[96];
  __shared__ float s_sb[96];
  for (int c = t; c < Ci; c += 256) {
    float2 cf = bn_coeff(psum, psq, bn_g, bn_b, c);
    s_sc[c] = cf.x; s_sb[c] = cf.y;
  }
  __syncthreads();

  const float* xb = y + ((size_t)b * Ci) * NPIX + n;

  if (slice < NH) {             // h path: 4 channels x 2 px
    const int d0 = slice * 4;
    float a[4][2];
#pragma unroll
    for (int j = 0; j < 4; ++j) { a[j][0] = bh[d0 + j]; a[j][1] = bh[d0 + j]; }
    const float* wr = wh + d0;
#pragma unroll 2
    for (int c = 0; c < Ci; ++c) {
      float2 xv = *(const float2*)(xb + (size_t)c * NPIX);
      float s = s_sc[c], o = s_sb[c];
      float x0 = fmaxf(xv.x * s + o, 0.f);
      float x1 = fmaxf(xv.y * s + o, 0.f);
#pragma unroll
      for (int j = 0; j < 4; ++j) {
        float wj = wr[j];
        a[j][0] += x0 * wj; a[j][1] += x1 * wj;
      }
      wr += Co;
    }
    __hip_bfloat16* yb = h3 + ((size_t)(b * (NPIX / 32) + (n >> 5)) * Co + d0) * 32 + (n & 31);
#pragma unroll
    for (int j = 0; j < 4; ++j) {
      __hip_bfloat162 tv;
      tv.x = __float2bfloat16(a[j][0]); tv.y = __float2bfloat16(a[j][1]);
      *(unsigned*)(yb + j * 32) = *(unsigned*)&tv;
    }
  } else {                      // f/g path: 2 channels each of f and g
    const int j0 = (slice - NH) * 2;
    float fa[2][2], ga[2][2];
#pragma unroll
    for (int j = 0; j < 2; ++j) {
      fa[j][0] = fa[j][1] = bfv[j0 + j];
      ga[j][0] = ga[j][1] = bgv[j0 + j];
    }
#pragma unroll 2
    for (int c = 0; c < Ci; ++c) {
      float2 xv = *(const float2*)(xb + (size_t)c * NPIX);
      float s = s_sc[c], o = s_sb[c];
      float x0 = fmaxf(xv.x * s + o, 0.f);
      float x1 = fmaxf(xv.y * s + o, 0.f);
#pragma unroll
      for (int j = 0; j < 2; ++j) {
        float wfv = wf[(size_t)c * CF + j0 + j];
        float wgv = wg[(size_t)c * CF + j0 + j];
        fa[j][0] += x0 * wfv; fa[j][1] += x1 * wfv;
        ga[j][0] += x0 * wgv; ga[j][1] += x1 * wgv;
      }
    }
#pragma unroll
    for (int px = 0; px < 2; ++px) {
      __hip_bfloat162 tf, tg;
      tf.x = __float2bfloat16(fa[0][px]); tf.y = __float2bfloat16(fa[1][px]);
      tg.x = __float2bfloat16(ga[0][px]); tg.y = __float2bfloat16(ga[1][px]);
      *(unsigned*)(fqT + ((size_t)b * NPIX + n + px) * FW + j0) = *(unsigned*)&tf;
      *(unsigned*)(gqT + ((size_t)b * NPIX + n + px) * FW + j0) = *(unsigned*)&tg;
    }
  }
}

// ---------------------------------------------------------------------------
// MFMA flash attention partial, wave-per-32q, no barriers.
// QK uses K=16 MFMA when available (f/g rows FW wide); h3 coalesced + tile-
// start prefetch; bf16 pacc. Grid: (NPIX/128, MS, NB), 256 threads.
// ---------------------------------------------------------------------------
template <int CO>
__global__ __launch_bounds__(256) void attn_mfma_k(
    const __hip_bfloat16* __restrict__ fqT, const __hip_bfloat16* __restrict__ gqT,
    const __hip_bfloat16* __restrict__ hq,
    __hip_bfloat16* __restrict__ pacc, float* __restrict__ pl) {
  constexpr int CSUB = CO / 16;
  __shared__ __align__(16) unsigned short Pw[4][2][32][64];   // 32 KB, XOR-swizzled

  const int t = threadIdx.x;
  const int wave = t >> 6, lane = t & 63, lq = lane & 15, lg = lane >> 4;
  const int ms = blockIdx.y, b = blockIdx.z;
  const int q0 = blockIdx.x * 128 + wave * 32;

#if QK_K16
  bf16x4 ff[2];
#pragma unroll
  for (int qs = 0; qs < 2; ++qs)
    ff[qs] = *reinterpret_cast<const bf16x4*>(
        fqT + ((size_t)b * NPIX + q0 + qs * 16 + lq) * FW + lg * 4);
#else
  bf16x8 ff[2];
#pragma unroll
  for (int qs = 0; qs < 2; ++qs)
    ff[qs] = *reinterpret_cast<const bf16x8*>(
        fqT + ((size_t)b * NPIX + q0 + qs * 16 + lq) * FW + lg * 8);
#endif

  f32x4 acc[2][CSUB];
#pragma unroll
  for (int qs = 0; qs < 2; ++qs)
#pragma unroll
    for (int cs = 0; cs < CSUB; ++cs) acc[qs][cs] = f32x4{0.f, 0.f, 0.f, 0.f};
  float ls[2] = {0.f, 0.f};

  const __hip_bfloat16* h3b = hq + (size_t)b * (NPIX / 32) * CO * 32;
  const int mbeg = ms * (NPIX / MS);

  for (int tile = 0; tile < (NPIX / MS) / 64; ++tile) {
    const int mt = mbeg + tile * 64;
    char* Pb = (char*)&Pw[wave][tile & 1][0][0];

    bf16x8 hv[2][CSUB];
#pragma unroll
    for (int kc = 0; kc < 2; ++kc)
#pragma unroll
      for (int cs = 0; cs < CSUB; ++cs)
        hv[kc][cs] = *reinterpret_cast<const bf16x8*>(
            h3b + ((size_t)((mt >> 5) + kc) * CO + cs * 16 + lq) * 32 + lg * 8);

#pragma unroll
    for (int msub = 0; msub < 4; ++msub) {
#if QK_K16
      bf16x4 ga = *reinterpret_cast<const bf16x4*>(
          gqT + ((size_t)b * NPIX + mt + msub * 16 + lq) * FW + lg * 4);
#else
      bf16x8 ga = *reinterpret_cast<const bf16x8*>(
          gqT + ((size_t)b * NPIX + mt + msub * 16 + lq) * FW + lg * 8);
#endif
#pragma unroll
      for (int qs = 0; qs < 2; ++qs) {
        f32x4 z = {0.f, 0.f, 0.f, 0.f};
#if QK_K16
        f32x4 S = __builtin_amdgcn_mfma_f32_16x16x16bf16_1k(ga, ff[qs], z, 0, 0, 0);
#else
        f32x4 S = __builtin_amdgcn_mfma_f32_16x16x32_bf16(ga, ff[qs], z, 0, 0, 0);
#endif
        float p0 = __expf(fminf(S[0], 60.f));
        float p1 = __expf(fminf(S[1], 60.f));
        float p2 = __expf(fminf(S[2], 60.f));
        float p3 = __expf(fminf(S[3], 60.f));
        ls[qs] += (p0 + p1) + (p2 + p3);
        __hip_bfloat162 t0, t1;
        t0.x = __float2bfloat16(p0); t0.y = __float2bfloat16(p1);
        t1.x = __float2bfloat16(p2); t1.y = __float2bfloat16(p3);
        uint2 wv;
        wv.x = *(unsigned*)&t0; wv.y = *(unsigned*)&t1;
        const int row = qs * 16 + lq;
        int byte = row * 128 + msub * 32 + lg * 8;
        byte ^= (row & 7) << 4;
        *(uint2*)(Pb + byte) = wv;
      }
    }
#pragma unroll
    for (int kc = 0; kc < 2; ++kc) {
      bf16x8 pa[2];
#pragma unroll
      for (int qs = 0; qs < 2; ++qs) {
        const int row = qs * 16 + lq;
        int byte = row * 128 + kc * 64 + lg * 16;
        byte ^= (row & 7) << 4;
        pa[qs] = *reinterpret_cast<const bf16x8*>(Pb + byte);
      }
#pragma unroll
      for (int cs = 0; cs < CSUB; ++cs)
#pragma unroll
        for (int qs = 0; qs < 2; ++qs)
          acc[qs][cs] = __builtin_amdgcn_mfma_f32_16x16x32_bf16(pa[qs], hv[kc][cs], acc[qs][cs], 0, 0, 0);
    }
  }

#pragma unroll
  for (int qs = 0; qs < 2; ++qs) {
    ls[qs] += __shfl_xor(ls[qs], 16);
    ls[qs] += __shfl_xor(ls[qs], 32);
  }
  const size_t lbase = ((size_t)ms * NB + b) * NPIX;
  if (lane < 16) {
    pl[lbase + q0 + lq]      = ls[0];
    pl[lbase + q0 + 16 + lq] = ls[1];
  }

  const size_t obase = (((size_t)ms * NB + b) * CO) * NPIX;
#pragma unroll
  for (int qs = 0; qs < 2; ++qs)
#pragma unroll
    for (int cs = 0; cs < CSUB; ++cs) {
      __hip_bfloat162 v0, v1;
      v0.x = __float2bfloat16(acc[qs][cs][0]); v0.y = __float2bfloat16(acc[qs][cs][1]);
      v1.x = __float2bfloat16(acc[qs][cs][2]); v1.y = __float2bfloat16(acc[qs][cs][3]);
      uint2 st; st.x = *(unsigned*)&v0; st.y = *(unsigned*)&v1;
      *(uint2*)&pacc[obase + (size_t)(cs * 16 + lq) * NPIX + q0 + qs * 16 + 4 * lg] = st;
    }
}

// ---------------------------------------------------------------------------
// Attention combine: merge MS bf16 partials, normalize, gamma + residual
// (BN+ReLU of y inline). 4 pixels/thread.
// ---------------------------------------------------------------------------
template <int CO>
__global__ __launch_bounds__(256) void attn_combine2_k(
    const __hip_bfloat16* __restrict__ pacc, const float* __restrict__ pl,
    const float* __restrict__ y,
    const float* __restrict__ psum, const float* __restrict__ psq,
    const float* __restrict__ bn_g, const float* __restrict__ bn_b,
    const float* __restrict__ gam, float* __restrict__ xout) {
  int i4 = blockIdx.x * 256 + threadIdx.x;   // over NB*CO*NPIX/4
  int n  = (i4 & 1023) * 4;
  int bc = i4 >> 10;
  int b  = bc / CO, c = bc - b * CO;
  float4 o = {0.f, 0.f, 0.f, 0.f};
  float4 L = {0.f, 0.f, 0.f, 0.f};
#pragma unroll
  for (int m = 0; m < MS; ++m) {
    ushort4 pa = *(const ushort4*)&pacc[(((size_t)m * NB + b) * CO + c) * NPIX + n];
    float4 lv = *(const float4*)&pl[((size_t)m * NB + b) * NPIX + n];
    o.x += bf2f(pa.x); o.y += bf2f(pa.y); o.z += bf2f(pa.z); o.w += bf2f(pa.w);
    L.x += lv.x; L.y += lv.y; L.z += lv.z; L.w += lv.w;
  }
  float2 cf = bn_coeff(psum, psq, bn_g, bn_b, c);
  size_t xi = ((size_t)b * CO + c) * NPIX + n;
  float4 yv = *(const float4*)&y[xi];
  float gm = gam[0];
  float4 r;
  r.x = gm * (o.x / L.x) + fmaxf(yv.x * cf.x + cf.y, 0.f);
  r.y = gm * (o.y / L.y) + fmaxf(yv.y * cf.x + cf.y, 0.f);
  r.z = gm * (o.z / L.z) + fmaxf(yv.z * cf.x + cf.y, 0.f);
  r.w = gm * (o.w / L.w) + fmaxf(yv.w * cf.x + cf.y, 0.f);
  *(float4*)&xout[xi] = r;
}

// ---------------------------------------------------------------------------
// Final: BN apply + ReLU + GAP over bf16 y; coeff computed inline per block.
// ---------------------------------------------------------------------------
__global__ __launch_bounds__(256) void bn_relu_gap_k(
    const __hip_bfloat16* __restrict__ y,
    const float* __restrict__ psum, const float* __restrict__ psq,
    const float* __restrict__ bn_g, const float* __restrict__ bn_b,
    float* __restrict__ out, int C) {
  int d = blockIdx.x;
  int b = blockIdx.y;
  int tid = threadIdx.x;
  float2 cf = bn_coeff(psum, psq, bn_g, bn_b, d);
  const __hip_bfloat16* yr = y + ((size_t)b * C + d) * NPIX;
  float s = 0.f;
  for (int n4 = tid; n4 < NPIX / 4; n4 += 256) {
    ushort4 v = *(const ushort4*)&yr[n4 * 4];
    s += fmaxf(bf2f(v.x) * cf.x + cf.y, 0.f) + fmaxf(bf2f(v.y) * cf.x + cf.y, 0.f) +
         fmaxf(bf2f(v.z) * cf.x + cf.y, 0.f) + fmaxf(bf2f(v.w) * cf.x + cf.y, 0.f);
  }
  __shared__ float sh[256];
  sh[tid] = s;
  __syncthreads();
  for (int st = 128; st > 0; st >>= 1) {
    if (tid < st) sh[tid] += sh[tid + st];
    __syncthreads();
  }
  if (tid == 0) out[(size_t)b * C + d] = sh[0] * (1.f / NPIX);
}

// ---------------------------------------------------------------------------
// Host side
// ---------------------------------------------------------------------------
extern "C" void kernel_launch(void* const* d_in, const int* in_sizes, int n_in,
                              void* d_out, int out_size, void* d_ws, size_t ws_size,
                              hipStream_t stream) {
  const float* x    = (const float*)d_in[0];
  const float* wfin = (const float*)d_in[34];
  const float* bnfg = (const float*)d_in[35];
  const float* bnfb = (const float*)d_in[36];

  float* ws = (float*)d_ws;
  size_t off = 0;
  float* y    = ws + off; off += (size_t)NB * 512 * NPIX;   // fp32 stage y / bf16 final y
  float* xo   = ws + off; off += (size_t)NB * 96 * NPIX;
  __hip_bfloat16* fqT = (__hip_bfloat16*)(ws + off); off += (size_t)NB * NPIX * 16;
  __hip_bfloat16* gqT = (__hip_bfloat16*)(ws + off); off += (size_t)NB * NPIX * 16;
  __hip_bfloat16* hq  = (__hip_bfloat16*)(ws + off); off += (size_t)NB * 48 * NPIX;
  float* psum = ws + off; off += 512 * NPART;
  float* psq  = ws + off; off += 512 * NPART;
  float* pl   = ws + off; off += (size_t)MS * NB * NPIX;
  __hip_bfloat16* pacc = (__hip_bfloat16*)(ws + off); off += (size_t)MS * NB * NPIX * 96 / 2;

  const int Ci_arr[3] = {3, 32, 64};
  const int Co_arr[3] = {32, 64, 96};
  const float* cur = x;
  for (int i = 0; i < 3; ++i) {
    const float* const* p = (const float* const*)(d_in + 1 + i * 11);
    const float* w     = p[0];
    const float* bconv = p[1];
    const float* bn_g  = p[2];
    const float* bn_b  = p[3];
    const float* awf   = p[4];
    const float* abf   = p[5];
    const float* awg   = p[6];
    const float* abg   = p[7];
    const float* awh   = p[8];
    const float* abh   = p[9];
    const float* gam   = p[10];
    int Ci = Ci_arr[i], Co = Co_arr[i];
    int CF = Co / 8;

    conv_stats_k<2, 2, false><<<dim3(8, Co / 2, NB), 256, 0, stream>>>(
        cur, w, bconv, y, psum, psq, Ci, Co);

    dim3 qg(8, Co / 4 + CF / 2 + 1, NB);
    if (i == 0)      qkv_k<4><<<qg, 256, 0, stream>>>(y, psum, psq, bn_g, bn_b, awh, abh, awf, abf, awg, abg, hq, fqT, gqT, Co, Co);
    else if (i == 1) qkv_k<8><<<qg, 256, 0, stream>>>(y, psum, psq, bn_g, bn_b, awh, abh, awf, abf, awg, abg, hq, fqT, gqT, Co, Co);
    else             qkv_k<12><<<qg, 256, 0, stream>>>(y, psum, psq, bn_g, bn_b, awh, abh, awf, abf, awg, abg, hq, fqT, gqT, Co, Co);

    dim3 ag(NPIX / 128, MS, NB);
    if (Co == 32) {
      attn_mfma_k<32><<<ag, 256, 0, stream>>>(fqT, gqT, hq, pacc, pl);
      attn_combine2_k<32><<<(NB * 32 * NPIX) / 1024, 256, 0, stream>>>(pacc, pl, y, psum, psq, bn_g, bn_b, gam, xo);
    } else if (Co == 64) {
      attn_mfma_k<64><<<ag, 256, 0, stream>>>(fqT, gqT, hq, pacc, pl);
      attn_combine2_k<64><<<(NB * 64 * NPIX) / 1024, 256, 0, stream>>>(pacc, pl, y, psum, psq, bn_g, bn_b, gam, xo);
    } else {
      attn_mfma_k<96><<<ag, 256, 0, stream>>>(fqT, gqT, hq, pacc, pl);
      attn_combine2_k<96><<<(NB * 96 * NPIX) / 1024, 256, 0, stream>>>(pacc, pl, y, psum, psq, bn_g, bn_b, gam, xo);
    }
    cur = xo;
  }

  // final: conv(96->512, no bias) + stats (bf16 y), then BN+ReLU+GAP
  conv_stats_k<8, 2, true><<<dim3(8, 512 / 8, NB), 256, 0, stream>>>(
      cur, wfin, nullptr, y, psum, psq, 96, 512);
  bn_relu_gap_k<<<dim3(512, NB), 256, 0, stream>>>(
      (const __hip_bfloat16*)y, psum, psq, bnfg, bnfb, (float*)d_out, 512);
}

// Round 12
// 169.601 us; speedup vs baseline: 1.0827x; 1.0827x over previous
//
#include <hip/hip_runtime.h>
#include <hip/hip_bf16.h>

constexpr int NPIX = 4096;   // H*W
constexpr int NB   = 2;      // batch
constexpr int MS   = 8;      // m-split for attention (grid.y)
constexpr int NPART  = 16;   // BN partials per channel

typedef __attribute__((ext_vector_type(8))) short bf16x8;
typedef __attribute__((ext_vector_type(4))) float f32x4;

__device__ inline float bf2f(unsigned short u) {
  unsigned v = (unsigned)u << 16;
  return __builtin_bit_cast(float, v);
}

// ---------------------------------------------------------------------------
// Per-channel fused BN affine from partials: sc = rstd*g, sb = bb - mean*sc
// ---------------------------------------------------------------------------
__device__ inline float2 bn_coeff(const float* __restrict__ psum, const float* __restrict__ psq,
                                  const float* __restrict__ g, const float* __restrict__ bb, int c) {
  float s = 0.f, s2 = 0.f;
#pragma unroll
  for (int p = 0; p < NPART; ++p) {
    s  += psum[(size_t)c * NPART + p];
    s2 += psq [(size_t)c * NPART + p];
  }
  const float inv = 1.f / (NB * NPIX);
  float m = s * inv;
  float var = s2 * inv - m * m;
  float r = rsqrtf(var + 1e-5f) * g[c];
  return float2{r, bb[c] - m * r};
}

// ---------------------------------------------------------------------------
// conv1x1 fp32 + fused BN partial stats. Optional bf16 y output (stats stay
// exact fp32 from registers). CPT out-channels x PX=2 pixels per thread.
// grid = (8, Co/CPT, NB).
// ---------------------------------------------------------------------------
template <int CPT, int PX, bool BF16OUT>
__global__ __launch_bounds__(256) void conv_stats_k(
    const float* __restrict__ x, const float* __restrict__ w,
    const float* __restrict__ bias, void* __restrict__ yout,
    float* __restrict__ psum, float* __restrict__ psq, int Ci, int Co) {
  constexpr int XB = NPIX / (256 * PX);
  const int t  = threadIdx.x;
  const int n  = (blockIdx.x * 256 + t) * PX;
  const int d0 = blockIdx.y * CPT;
  const int b  = blockIdx.z;
  float a[CPT][PX];
#pragma unroll
  for (int j = 0; j < CPT; ++j) {
    float bv = bias ? bias[d0 + j] : 0.f;
#pragma unroll
    for (int p = 0; p < PX; ++p) a[j][p] = bv;
  }
  const float* xb = x + ((size_t)b * Ci) * NPIX + n;
  const float* wr = w + d0;
#pragma unroll 2
  for (int c = 0; c < Ci; ++c) {
    float xv[PX];
    if constexpr (PX == 2) *(float2*)xv = *(const float2*)(xb + (size_t)c * NPIX);
    else                   *(float4*)xv = *(const float4*)(xb + (size_t)c * NPIX);
#pragma unroll
    for (int j = 0; j < CPT; ++j) {
      float wj = wr[j];
#pragma unroll
      for (int p = 0; p < PX; ++p) a[j][p] += xv[p] * wj;
    }
    wr += Co;
  }
  if constexpr (BF16OUT) {
    __hip_bfloat16* yb = (__hip_bfloat16*)yout + ((size_t)b * Co + d0) * NPIX + n;
#pragma unroll
    for (int j = 0; j < CPT; ++j) {
      __hip_bfloat162 tv;
      tv.x = __float2bfloat16(a[j][0]); tv.y = __float2bfloat16(a[j][1]);
      *(unsigned*)(yb + (size_t)j * NPIX) = *(unsigned*)&tv;
    }
  } else {
    float* yb = (float*)yout + ((size_t)b * Co + d0) * NPIX + n;
#pragma unroll
    for (int j = 0; j < CPT; ++j) {
      if constexpr (PX == 2) *(float2*)(yb + (size_t)j * NPIX) = *(float2*)a[j];
      else                   *(float4*)(yb + (size_t)j * NPIX) = *(float4*)a[j];
    }
  }

  float s[CPT], s2[CPT];
#pragma unroll
  for (int j = 0; j < CPT; ++j) {
    s[j] = 0.f; s2[j] = 0.f;
#pragma unroll
    for (int p = 0; p < PX; ++p) { s[j] += a[j][p]; s2[j] += a[j][p] * a[j][p]; }
  }
#pragma unroll
  for (int j = 0; j < CPT; ++j) {
    for (int d = 1; d < 64; d <<= 1) {
      s[j]  += __shfl_xor(s[j], d);
      s2[j] += __shfl_xor(s2[j], d);
    }
  }
  __shared__ float shA[4][CPT];
  __shared__ float shB[4][CPT];
  const int wave = t >> 6, lane = t & 63;
  if (lane == 0) {
#pragma unroll
    for (int j = 0; j < CPT; ++j) { shA[wave][j] = s[j]; shB[wave][j] = s2[j]; }
  }
  __syncthreads();
  if (t < CPT) {
    const int p = b * XB + blockIdx.x;
    psum[(size_t)(d0 + t) * NPART + p] = (shA[0][t] + shA[1][t]) + (shA[2][t] + shA[3][t]);
    psq [(size_t)(d0 + t) * NPART + p] = (shB[0][t] + shB[1][t]) + (shB[2][t] + shB[3][t]);
  }
}

// ---------------------------------------------------------------------------
// Fused q/k/v producer (round-10 slicing: occupancy-first).
// blockIdx.y slices:
//   [0, Co/2)          : h conv, 2 channels x 2 pixels -> h3 [B][N/32][CO][32]
//   [Co/2, Co/2+CF)    : one f-channel + one g-channel x 2 pixels -> fqT/gqT
//   Co/2+CF            : zero the channel pads [CF,32) of fqT/gqT
// grid = (8, Co/2+CF+1, NB), 256 threads.
// ---------------------------------------------------------------------------
template <int CF>
__global__ __launch_bounds__(256) void qkv_k(
    const float* __restrict__ y,
    const float* __restrict__ psum, const float* __restrict__ psq,
    const float* __restrict__ bn_g, const float* __restrict__ bn_b,
    const float* __restrict__ wh, const float* __restrict__ bh,
    const float* __restrict__ wf, const float* __restrict__ bfv,
    const float* __restrict__ wg, const float* __restrict__ bgv,
    __hip_bfloat16* __restrict__ h3, __hip_bfloat16* __restrict__ fqT,
    __hip_bfloat16* __restrict__ gqT, int Ci, int Co) {
  const int t = threadIdx.x;
  const int n = (blockIdx.x * 256 + t) * 2;
  const int b = blockIdx.z;
  const int slice = blockIdx.y;

  if (slice == Co / 2 + CF) {   // pad-zero slice
#pragma unroll
    for (int px = 0; px < 2; ++px) {
      __hip_bfloat16* fp = fqT + (((size_t)b * NPIX + n + px) << 5);
      __hip_bfloat16* gp = gqT + (((size_t)b * NPIX + n + px) << 5);
      for (int j = CF; j < 32; j += 2) {
        *(unsigned*)(fp + j) = 0u;
        *(unsigned*)(gp + j) = 0u;
      }
    }
    return;
  }

  __shared__ float s_sc[96];
  __shared__ float s_sb[96];
  for (int c = t; c < Ci; c += 256) {
    float2 cf = bn_coeff(psum, psq, bn_g, bn_b, c);
    s_sc[c] = cf.x; s_sb[c] = cf.y;
  }
  __syncthreads();

  const float* xb = y + ((size_t)b * Ci) * NPIX + n;

  if (slice < Co / 2) {         // h path
    const int d0 = slice * 2;
    float2 a0 = {bh[d0], bh[d0]};
    float2 a1 = {bh[d0 + 1], bh[d0 + 1]};
    const float* wr = wh + d0;
#pragma unroll 4
    for (int c = 0; c < Ci; ++c) {
      float2 xv = *(const float2*)(xb + (size_t)c * NPIX);
      float s = s_sc[c], o = s_sb[c];
      xv.x = fmaxf(xv.x * s + o, 0.f);
      xv.y = fmaxf(xv.y * s + o, 0.f);
      float w0 = wr[0], w1 = wr[1];
      a0.x += xv.x * w0; a0.y += xv.y * w0;
      a1.x += xv.x * w1; a1.y += xv.y * w1;
      wr += Co;
    }
    __hip_bfloat16* yb = h3 + ((size_t)(b * (NPIX / 32) + (n >> 5)) * Co + d0) * 32 + (n & 31);
    __hip_bfloat162 t0, t1;
    t0.x = __float2bfloat16(a0.x); t0.y = __float2bfloat16(a0.y);
    t1.x = __float2bfloat16(a1.x); t1.y = __float2bfloat16(a1.y);
    *(unsigned*)yb        = *(unsigned*)&t0;
    *(unsigned*)(yb + 32) = *(unsigned*)&t1;
  } else {                      // f/g path: one channel j of each
    const int j = slice - Co / 2;
    float f0 = bfv[j], f1 = bfv[j], g0 = bgv[j], g1 = bgv[j];
#pragma unroll 4
    for (int c = 0; c < Ci; ++c) {
      float2 xv = *(const float2*)(xb + (size_t)c * NPIX);
      float s = s_sc[c], o = s_sb[c];
      xv.x = fmaxf(xv.x * s + o, 0.f);
      xv.y = fmaxf(xv.y * s + o, 0.f);
      float wfv = wf[(size_t)c * CF + j], wgv = wg[(size_t)c * CF + j];
      f0 += xv.x * wfv; f1 += xv.y * wfv;
      g0 += xv.x * wgv; g1 += xv.y * wgv;
    }
    fqT[(((size_t)b * NPIX + n)     << 5) + j] = __float2bfloat16(f0);
    fqT[(((size_t)b * NPIX + n + 1) << 5) + j] = __float2bfloat16(f1);
    gqT[(((size_t)b * NPIX + n)     << 5) + j] = __float2bfloat16(g0);
    gqT[(((size_t)b * NPIX + n + 1) << 5) + j] = __float2bfloat16(g1);
  }
}

// ---------------------------------------------------------------------------
// MFMA flash attention partial, wave-per-32q, no barriers.
// h3 layout -> coalesced hv; hv prefetched at tile start; bf16 pacc.
// Grid: (NPIX/128, MS, NB), 256 threads. pacc [MS][B][CO][N] bf16, pl fp32.
// ---------------------------------------------------------------------------
template <int CO>
__global__ __launch_bounds__(256) void attn_mfma_k(
    const __hip_bfloat16* __restrict__ fqT, const __hip_bfloat16* __restrict__ gqT,
    const __hip_bfloat16* __restrict__ hq,
    __hip_bfloat16* __restrict__ pacc, float* __restrict__ pl) {
  constexpr int CSUB = CO / 16;
  __shared__ __align__(16) unsigned short Pw[4][2][32][64];   // 32 KB, XOR-swizzled

  const int t = threadIdx.x;
  const int wave = t >> 6, lane = t & 63, lq = lane & 15, lg = lane >> 4;
  const int ms = blockIdx.y, b = blockIdx.z;
  const int q0 = blockIdx.x * 128 + wave * 32;

  bf16x8 ff[2];
#pragma unroll
  for (int qs = 0; qs < 2; ++qs)
    ff[qs] = *reinterpret_cast<const bf16x8*>(
        fqT + (((size_t)b * NPIX + q0 + qs * 16 + lq) << 5) + lg * 8);

  f32x4 acc[2][CSUB];
#pragma unroll
  for (int qs = 0; qs < 2; ++qs)
#pragma unroll
    for (int cs = 0; cs < CSUB; ++cs) acc[qs][cs] = f32x4{0.f, 0.f, 0.f, 0.f};
  float ls[2] = {0.f, 0.f};

  const __hip_bfloat16* h3b = hq + (size_t)b * (NPIX / 32) * CO * 32;
  const int mbeg = ms * (NPIX / MS);

  for (int tile = 0; tile < (NPIX / MS) / 64; ++tile) {
    const int mt = mbeg + tile * 64;
    char* Pb = (char*)&Pw[wave][tile & 1][0][0];

    bf16x8 hv[2][CSUB];
#pragma unroll
    for (int kc = 0; kc < 2; ++kc)
#pragma unroll
      for (int cs = 0; cs < CSUB; ++cs)
        hv[kc][cs] = *reinterpret_cast<const bf16x8*>(
            h3b + ((size_t)((mt >> 5) + kc) * CO + cs * 16 + lq) * 32 + lg * 8);

#pragma unroll
    for (int msub = 0; msub < 4; ++msub) {
      bf16x8 ga = *reinterpret_cast<const bf16x8*>(
          gqT + (((size_t)b * NPIX + mt + msub * 16 + lq) << 5) + lg * 8);
#pragma unroll
      for (int qs = 0; qs < 2; ++qs) {
        f32x4 z = {0.f, 0.f, 0.f, 0.f};
        f32x4 S = __builtin_amdgcn_mfma_f32_16x16x32_bf16(ga, ff[qs], z, 0, 0, 0);
        float p0 = __expf(fminf(S[0], 60.f));
        float p1 = __expf(fminf(S[1], 60.f));
        float p2 = __expf(fminf(S[2], 60.f));
        float p3 = __expf(fminf(S[3], 60.f));
        ls[qs] += (p0 + p1) + (p2 + p3);
        __hip_bfloat162 t0, t1;
        t0.x = __float2bfloat16(p0); t0.y = __float2bfloat16(p1);
        t1.x = __float2bfloat16(p2); t1.y = __float2bfloat16(p3);
        uint2 wv;
        wv.x = *(unsigned*)&t0; wv.y = *(unsigned*)&t1;
        const int row = qs * 16 + lq;
        int byte = row * 128 + msub * 32 + lg * 8;
        byte ^= (row & 7) << 4;
        *(uint2*)(Pb + byte) = wv;
      }
    }
#pragma unroll
    for (int kc = 0; kc < 2; ++kc) {
      bf16x8 pa[2];
#pragma unroll
      for (int qs = 0; qs < 2; ++qs) {
        const int row = qs * 16 + lq;
        int byte = row * 128 + kc * 64 + lg * 16;
        byte ^= (row & 7) << 4;
        pa[qs] = *reinterpret_cast<const bf16x8*>(Pb + byte);
      }
#pragma unroll
      for (int cs = 0; cs < CSUB; ++cs)
#pragma unroll
        for (int qs = 0; qs < 2; ++qs)
          acc[qs][cs] = __builtin_amdgcn_mfma_f32_16x16x32_bf16(pa[qs], hv[kc][cs], acc[qs][cs], 0, 0, 0);
    }
  }

#pragma unroll
  for (int qs = 0; qs < 2; ++qs) {
    ls[qs] += __shfl_xor(ls[qs], 16);
    ls[qs] += __shfl_xor(ls[qs], 32);
  }
  const size_t lbase = ((size_t)ms * NB + b) * NPIX;
  if (lane < 16) {
    pl[lbase + q0 + lq]      = ls[0];
    pl[lbase + q0 + 16 + lq] = ls[1];
  }

  const size_t obase = (((size_t)ms * NB + b) * CO) * NPIX;
#pragma unroll
  for (int qs = 0; qs < 2; ++qs)
#pragma unroll
    for (int cs = 0; cs < CSUB; ++cs) {
      __hip_bfloat162 v0, v1;
      v0.x = __float2bfloat16(acc[qs][cs][0]); v0.y = __float2bfloat16(acc[qs][cs][1]);
      v1.x = __float2bfloat16(acc[qs][cs][2]); v1.y = __float2bfloat16(acc[qs][cs][3]);
      uint2 st; st.x = *(unsigned*)&v0; st.y = *(unsigned*)&v1;
      *(uint2*)&pacc[obase + (size_t)(cs * 16 + lq) * NPIX + q0 + qs * 16 + 4 * lg] = st;
    }
}

// ---------------------------------------------------------------------------
// Attention combine: merge MS bf16 partials, normalize, gamma + residual
// (BN+ReLU of y inline). 4 pixels/thread.
// ---------------------------------------------------------------------------
template <int CO>
__global__ __launch_bounds__(256) void attn_combine2_k(
    const __hip_bfloat16* __restrict__ pacc, const float* __restrict__ pl,
    const float* __restrict__ y,
    const float* __restrict__ psum, const float* __restrict__ psq,
    const float* __restrict__ bn_g, const float* __restrict__ bn_b,
    const float* __restrict__ gam, float* __restrict__ xout) {
  int i4 = blockIdx.x * 256 + threadIdx.x;   // over NB*CO*NPIX/4
  int n  = (i4 & 1023) * 4;
  int bc = i4 >> 10;
  int b  = bc / CO, c = bc - b * CO;
  float4 o = {0.f, 0.f, 0.f, 0.f};
  float4 L = {0.f, 0.f, 0.f, 0.f};
#pragma unroll
  for (int m = 0; m < MS; ++m) {
    ushort4 pa = *(const ushort4*)&pacc[(((size_t)m * NB + b) * CO + c) * NPIX + n];
    float4 lv = *(const float4*)&pl[((size_t)m * NB + b) * NPIX + n];
    o.x += bf2f(pa.x); o.y += bf2f(pa.y); o.z += bf2f(pa.z); o.w += bf2f(pa.w);
    L.x += lv.x; L.y += lv.y; L.z += lv.z; L.w += lv.w;
  }
  float2 cf = bn_coeff(psum, psq, bn_g, bn_b, c);
  size_t xi = ((size_t)b * CO + c) * NPIX + n;
  float4 yv = *(const float4*)&y[xi];
  float gm = gam[0];
  float4 r;
  r.x = gm * (o.x / L.x) + fmaxf(yv.x * cf.x + cf.y, 0.f);
  r.y = gm * (o.y / L.y) + fmaxf(yv.y * cf.x + cf.y, 0.f);
  r.z = gm * (o.z / L.z) + fmaxf(yv.z * cf.x + cf.y, 0.f);
  r.w = gm * (o.w / L.w) + fmaxf(yv.w * cf.x + cf.y, 0.f);
  *(float4*)&xout[xi] = r;
}

// ---------------------------------------------------------------------------
// Final: BN apply + ReLU + GAP over bf16 y; coeff computed inline per block.
// ---------------------------------------------------------------------------
__global__ __launch_bounds__(256) void bn_relu_gap_k(
    const __hip_bfloat16* __restrict__ y,
    const float* __restrict__ psum, const float* __restrict__ psq,
    const float* __restrict__ bn_g, const float* __restrict__ bn_b,
    float* __restrict__ out, int C) {
  int d = blockIdx.x;
  int b = blockIdx.y;
  int tid = threadIdx.x;
  float2 cf = bn_coeff(psum, psq, bn_g, bn_b, d);
  const __hip_bfloat16* yr = y + ((size_t)b * C + d) * NPIX;
  float s = 0.f;
  for (int n4 = tid; n4 < NPIX / 4; n4 += 256) {
    ushort4 v = *(const ushort4*)&yr[n4 * 4];
    s += fmaxf(bf2f(v.x) * cf.x + cf.y, 0.f) + fmaxf(bf2f(v.y) * cf.x + cf.y, 0.f) +
         fmaxf(bf2f(v.z) * cf.x + cf.y, 0.f) + fmaxf(bf2f(v.w) * cf.x + cf.y, 0.f);
  }
  __shared__ float sh[256];
  sh[tid] = s;
  __syncthreads();
  for (int st = 128; st > 0; st >>= 1) {
    if (tid < st) sh[tid] += sh[tid + st];
    __syncthreads();
  }
  if (tid == 0) out[(size_t)b * C + d] = sh[0] * (1.f / NPIX);
}

// ---------------------------------------------------------------------------
// Host side
// ---------------------------------------------------------------------------
extern "C" void kernel_launch(void* const* d_in, const int* in_sizes, int n_in,
                              void* d_out, int out_size, void* d_ws, size_t ws_size,
                              hipStream_t stream) {
  const float* x    = (const float*)d_in[0];
  const float* wfin = (const float*)d_in[34];
  const float* bnfg = (const float*)d_in[35];
  const float* bnfb = (const float*)d_in[36];

  float* ws = (float*)d_ws;
  size_t off = 0;
  float* y    = ws + off; off += (size_t)NB * 512 * NPIX;   // fp32 stage y / bf16 final y
  float* xo   = ws + off; off += (size_t)NB * 96 * NPIX;
  __hip_bfloat16* fqT = (__hip_bfloat16*)(ws + off); off += (size_t)NB * NPIX * 16;
  __hip_bfloat16* gqT = (__hip_bfloat16*)(ws + off); off += (size_t)NB * NPIX * 16;
  __hip_bfloat16* hq  = (__hip_bfloat16*)(ws + off); off += (size_t)NB * 48 * NPIX;
  float* psum = ws + off; off += 512 * NPART;
  float* psq  = ws + off; off += 512 * NPART;
  float* pl   = ws + off; off += (size_t)MS * NB * NPIX;
  __hip_bfloat16* pacc = (__hip_bfloat16*)(ws + off); off += (size_t)MS * NB * NPIX * 96 / 2;

  const int Co_arr[3] = {32, 64, 96};
  const int Ci_arr[3] = {3, 32, 64};
  const float* cur = x;
  for (int i = 0; i < 3; ++i) {
    const float* const* p = (const float* const*)(d_in + 1 + i * 11);
    const float* w     = p[0];
    const float* bconv = p[1];
    const float* bn_g  = p[2];
    const float* bn_b  = p[3];
    const float* awf   = p[4];
    const float* abf   = p[5];
    const float* awg   = p[6];
    const float* abg   = p[7];
    const float* awh   = p[8];
    const float* abh   = p[9];
    const float* gam   = p[10];
    int Ci = Ci_arr[i], Co = Co_arr[i];
    int CF = Co / 8;

    conv_stats_k<2, 2, false><<<dim3(8, Co / 2, NB), 256, 0, stream>>>(
        cur, w, bconv, y, psum, psq, Ci, Co);

    dim3 qg(8, Co / 2 + CF + 1, NB);
    if (i == 0)      qkv_k<4><<<qg, 256, 0, stream>>>(y, psum, psq, bn_g, bn_b, awh, abh, awf, abf, awg, abg, hq, fqT, gqT, Co, Co);
    else if (i == 1) qkv_k<8><<<qg, 256, 0, stream>>>(y, psum, psq, bn_g, bn_b, awh, abh, awf, abf, awg, abg, hq, fqT, gqT, Co, Co);
    else             qkv_k<12><<<qg, 256, 0, stream>>>(y, psum, psq, bn_g, bn_b, awh, abh, awf, abf, awg, abg, hq, fqT, gqT, Co, Co);

    dim3 ag(NPIX / 128, MS, NB);
    if (Co == 32) {
      attn_mfma_k<32><<<ag, 256, 0, stream>>>(fqT, gqT, hq, pacc, pl);
      attn_combine2_k<32><<<(NB * 32 * NPIX) / 1024, 256, 0, stream>>>(pacc, pl, y, psum, psq, bn_g, bn_b, gam, xo);
    } else if (Co == 64) {
      attn_mfma_k<64><<<ag, 256, 0, stream>>>(fqT, gqT, hq, pacc, pl);
      attn_combine2_k<64><<<(NB * 64 * NPIX) / 1024, 256, 0, stream>>>(pacc, pl, y, psum, psq, bn_g, bn_b, gam, xo);
    } else {
      attn_mfma_k<96><<<ag, 256, 0, stream>>>(fqT, gqT, hq, pacc, pl);
      attn_combine2_k<96><<<(NB * 96 * NPIX) / 1024, 256, 0, stream>>>(pacc, pl, y, psum, psq, bn_g, bn_b, gam, xo);
    }
    cur = xo;
  }

  // final: conv(96->512, no bias) + stats (bf16 y), then BN+ReLU+GAP
  conv_stats_k<8, 2, true><<<dim3(8, 512 / 8, NB), 256, 0, stream>>>(
      cur, wfin, nullptr, y, psum, psq, 96, 512);
  bn_relu_gap_k<<<dim3(512, NB), 256, 0, stream>>>(
      (const __hip_bfloat16*)y, psum, psq, bnfg, bnfb, (float*)d_out, 512);
}